// Round 2
// baseline (169.538 us; speedup 1.0000x reference)
//
#include <hip/hip_runtime.h>
#include <hip/hip_bf16.h>
#include <float.h>

#define NB 8
#define NN 2048
#define DD 64
#define ROWS (NB*NN)   // 16384
#define NJC 16         // j chunks
#define JCH 128        // chunk size

// ---------------- Kernel 1: q = x@Wq ; k,v = x@Wkv ----------------
// lane = row (64 rows/block), wave = 48-col slice of the 192 outputs.
__global__ __launch_bounds__(256) void qkv_kernel(
    const float* __restrict__ x, const float* __restrict__ Wq,
    const float* __restrict__ Wkv,
    float* __restrict__ q, float* __restrict__ k, float* __restrict__ v) {
  __shared__ float Wt[192*64];   // transposed: Wt[c][d], 48KB
  const int tid = threadIdx.x;
  for (int i = tid; i < 192*64; i += 256) {
    int c = i >> 6, d = i & 63;
    Wt[i] = (c < 64) ? Wq[d*64 + c] : Wkv[d*128 + (c - 64)];
  }
  __syncthreads();
  const int lane = tid & 63;
  const int wv = tid >> 6;
  const long rg = (long)blockIdx.x * 64 + lane;
  float4 xr[16];
  const float4* xp = (const float4*)(x + rg*64);
#pragma unroll
  for (int d4 = 0; d4 < 16; ++d4) xr[d4] = xp[d4];
  const float4* Wt4 = (const float4*)Wt;
#pragma unroll 1
  for (int cg = 0; cg < 12; ++cg) {
    const int c0 = wv*48 + cg*4;
    float a0=0.f,a1=0.f,a2=0.f,a3=0.f;
#pragma unroll
    for (int d4 = 0; d4 < 16; ++d4) {
      float4 xv = xr[d4];
      float4 w0 = Wt4[(c0+0)*16 + d4];
      float4 w1 = Wt4[(c0+1)*16 + d4];
      float4 w2 = Wt4[(c0+2)*16 + d4];
      float4 w3 = Wt4[(c0+3)*16 + d4];
      a0 = fmaf(xv.x,w0.x,a0); a1 = fmaf(xv.x,w1.x,a1); a2 = fmaf(xv.x,w2.x,a2); a3 = fmaf(xv.x,w3.x,a3);
      a0 = fmaf(xv.y,w0.y,a0); a1 = fmaf(xv.y,w1.y,a1); a2 = fmaf(xv.y,w2.y,a2); a3 = fmaf(xv.y,w3.y,a3);
      a0 = fmaf(xv.z,w0.z,a0); a1 = fmaf(xv.z,w1.z,a1); a2 = fmaf(xv.z,w2.z,a2); a3 = fmaf(xv.z,w3.z,a3);
      a0 = fmaf(xv.w,w0.w,a0); a1 = fmaf(xv.w,w1.w,a1); a2 = fmaf(xv.w,w2.w,a2); a3 = fmaf(xv.w,w3.w,a3);
    }
    float* dst; int cc;
    if (c0 < 64)       { dst = q; cc = c0; }
    else if (c0 < 128) { dst = k; cc = c0 - 64; }
    else               { dst = v; cc = c0 - 128; }
    *(float4*)(dst + rg*64 + cc) = make_float4(a0,a1,a2,a3);
  }
}

// ---------------- Kernel 2: per-row argmax_j q_i . k_j (partial per j-chunk)
__global__ __launch_bounds__(256) void argmax_kernel(
    const float* __restrict__ q, const float* __restrict__ k,
    float* __restrict__ pmax, int* __restrict__ pidx) {
  __shared__ float ks[JCH*64];   // 32KB k chunk
  const int tid = threadIdx.x;
  const int jc = blockIdx.x;     // 0..15
  const int rb = blockIdx.y;     // 0..7
  const int b  = blockIdx.z;     // 0..7
  const int j0 = jc * JCH;
  const float4* ksrc = (const float4*)(k + ((long)b*NN + j0) * 64);
  float4* kdst = (float4*)ks;
#pragma unroll
  for (int i = 0; i < 8; ++i) kdst[tid + i*256] = ksrc[tid + i*256];
  const long rg = (long)b*NN + rb*256 + tid;
  float4 qr[16];
  const float4* qp = (const float4*)(q + rg*64);
#pragma unroll
  for (int d4 = 0; d4 < 16; ++d4) qr[d4] = qp[d4];
  __syncthreads();
  const float4* ks4 = (const float4*)ks;
  float best = -FLT_MAX; int bi = 0;
#pragma unroll 2
  for (int j = 0; j < JCH; ++j) {
    float a0=0.f,a1=0.f,a2=0.f,a3=0.f;
#pragma unroll
    for (int d4 = 0; d4 < 16; ++d4) {
      float4 kv = ks4[j*16 + d4];   // uniform address -> LDS broadcast
      float4 qv = qr[d4];
      a0 = fmaf(qv.x,kv.x,a0);
      a1 = fmaf(qv.y,kv.y,a1);
      a2 = fmaf(qv.z,kv.z,a2);
      a3 = fmaf(qv.w,kv.w,a3);
    }
    float dot = (a0+a1)+(a2+a3);
    bool gt = dot > best;          // strict >  => first max kept (matches np.argmax)
    best = gt ? dot : best;
    bi   = gt ? j   : bi;
  }
  pmax[(long)jc*ROWS + rg] = best;
  pidx[(long)jc*ROWS + rg] = j0 + bi;
}

// ---------------- Kernel 3: gather v[idx] -> LN -> MLP -> LN -> +x (fp32 out)
__global__ __launch_bounds__(256) void epilogue_kernel(
    const float* __restrict__ x, const float* __restrict__ v,
    const float* __restrict__ pmax, const int* __restrict__ pidx,
    const float* __restrict__ g1, const float* __restrict__ b1,
    const float* __restrict__ W1, const float* __restrict__ bin,
    const float* __restrict__ W2, const float* __restrict__ bout,
    const float* __restrict__ g2, const float* __restrict__ b2,
    float* __restrict__ out) {
  __shared__ float WaT[64*64];     // Wa^T = (W1[0:64]+W1[128:192])^T ; later reused for W2
  __shared__ float WbT[64*64];     // W1[64:128]^T
  __shared__ float mids[64*65];    // mid[row][m], pad 65 -> conflict-free
  __shared__ float2 sums[64*4];
  __shared__ float vecs[6*64];     // g1,b1,bin,bout,g2,b2
  const int tid = threadIdx.x;
  for (int i = tid; i < 4096; i += 256) {
    int m = i >> 6, d = i & 63;
    WaT[i] = W1[d*64 + m] + W1[(128+d)*64 + m];
    WbT[i] = W1[(64+d)*64 + m];
  }
  if (tid < 64) {
    vecs[tid]       = g1[tid];  vecs[64+tid]  = b1[tid];
    vecs[128+tid]   = bin[tid]; vecs[192+tid] = bout[tid];
    vecs[256+tid]   = g2[tid];  vecs[320+tid] = b2[tid];
  }
  __syncthreads();
  const int lane = tid & 63;
  const int wv = tid >> 6;
  const long rg = (long)blockIdx.x*64 + lane;
  // reduce chunk partials -> global argmax (ascending jc + strict > keeps first)
  float best = -FLT_MAX; int idx = 0;
#pragma unroll
  for (int jcc = 0; jcc < NJC; ++jcc) {
    float pm = pmax[(long)jcc*ROWS + rg];
    int   pi = pidx[(long)jcc*ROWS + rg];
    bool gt = pm > best;
    best = gt ? pm : best;
    idx  = gt ? pi : idx;
  }
  float nr[64], xr[64];
  const float4* vp = (const float4*)(v + ((rg >> 11)*(long)NN + idx)*64);
  const float4* xp = (const float4*)(x + rg*64);
#pragma unroll
  for (int d4 = 0; d4 < 16; ++d4) {
    float4 t = vp[d4];
    nr[d4*4+0]=t.x; nr[d4*4+1]=t.y; nr[d4*4+2]=t.z; nr[d4*4+3]=t.w;
    float4 u = xp[d4];
    xr[d4*4+0]=u.x; xr[d4*4+1]=u.y; xr[d4*4+2]=u.z; xr[d4*4+3]=u.w;
  }
  // LN1 (population var, eps 1e-5)
  float s=0.f, s2=0.f;
#pragma unroll
  for (int d = 0; d < 64; ++d) { s += nr[d]; s2 += nr[d]*nr[d]; }
  float mu  = s*(1.f/64.f);
  float inv = rsqrtf(s2*(1.f/64.f) - mu*mu + 1e-5f);
#pragma unroll
  for (int d = 0; d < 64; ++d) nr[d] = (nr[d]-mu)*inv*vecs[d] + vecs[64+d];
  // mid = relu(nr@Wa + xr@Wb + bin) ; wave handles its 16-m slice
  const float4* WaT4 = (const float4*)WaT;
  const float4* WbT4 = (const float4*)WbT;
#pragma unroll 1
  for (int mi = 0; mi < 16; ++mi) {
    const int m = wv*16 + mi;
    float a0=0.f,a1=0.f,a2=0.f,a3=0.f;
#pragma unroll
    for (int d4 = 0; d4 < 16; ++d4) {
      float4 wa = WaT4[m*16+d4];
      float4 wb = WbT4[m*16+d4];
      a0 = fmaf(nr[d4*4+0], wa.x, a0); a1 = fmaf(nr[d4*4+1], wa.y, a1);
      a2 = fmaf(nr[d4*4+2], wa.z, a2); a3 = fmaf(nr[d4*4+3], wa.w, a3);
      a0 = fmaf(xr[d4*4+0], wb.x, a0); a1 = fmaf(xr[d4*4+1], wb.y, a1);
      a2 = fmaf(xr[d4*4+2], wb.z, a2); a3 = fmaf(xr[d4*4+3], wb.w, a3);
    }
    mids[lane*65 + m] = fmaxf(vecs[128+m] + ((a0+a1)+(a2+a3)), 0.f);
  }
  __syncthreads();
  // overlay W2 into WaT (WaT dead now), natural [m][n] layout
  for (int i = tid; i < 4096; i += 256) WaT[i] = W2[i];
  __syncthreads();
  // rn = mid@W2 + bout ; wave handles its 16-n slice
  float rn[16];
#pragma unroll
  for (int n = 0; n < 16; ++n) rn[n] = vecs[192 + wv*16 + n];
  const float4* W2s4 = (const float4*)WaT;
#pragma unroll 1
  for (int m = 0; m < 64; ++m) {
    float mm = mids[lane*65 + m];
#pragma unroll
    for (int n4 = 0; n4 < 4; ++n4) {
      float4 w = W2s4[m*16 + wv*4 + n4];
      rn[n4*4+0] = fmaf(mm, w.x, rn[n4*4+0]);
      rn[n4*4+1] = fmaf(mm, w.y, rn[n4*4+1]);
      rn[n4*4+2] = fmaf(mm, w.z, rn[n4*4+2]);
      rn[n4*4+3] = fmaf(mm, w.w, rn[n4*4+3]);
    }
  }
  float ps=0.f, ps2=0.f;
#pragma unroll
  for (int n = 0; n < 16; ++n) { ps += rn[n]; ps2 += rn[n]*rn[n]; }
  sums[lane*4+wv] = make_float2(ps, ps2);
  __syncthreads();
  float ts=0.f, ts2=0.f;
#pragma unroll
  for (int w = 0; w < 4; ++w) { float2 p = sums[lane*4+w]; ts += p.x; ts2 += p.y; }
  float mu2  = ts*(1.f/64.f);
  float inv2 = rsqrtf(ts2*(1.f/64.f) - mu2*mu2 + 1e-5f);
  float ov[16];
#pragma unroll
  for (int n = 0; n < 16; ++n) ov[n] = (rn[n]-mu2)*inv2*vecs[256+wv*16+n] + vecs[320+wv*16+n] + xr[wv*16+n];
  // fp32 output: 16 floats per (lane, wave) at out[rg*64 + wv*16]
  float4* dst = (float4*)(out + rg*64 + wv*16);
  dst[0] = make_float4(ov[0], ov[1], ov[2], ov[3]);
  dst[1] = make_float4(ov[4], ov[5], ov[6], ov[7]);
  dst[2] = make_float4(ov[8], ov[9], ov[10], ov[11]);
  dst[3] = make_float4(ov[12],ov[13],ov[14],ov[15]);
}

extern "C" void kernel_launch(void* const* d_in, const int* in_sizes, int n_in,
                              void* d_out, int out_size, void* d_ws, size_t ws_size,
                              hipStream_t stream) {
  const float* x    = (const float*)d_in[0];
  const float* Wq   = (const float*)d_in[1];
  const float* Wkv  = (const float*)d_in[2];
  const float* g1   = (const float*)d_in[3];
  const float* b1   = (const float*)d_in[4];
  const float* W1   = (const float*)d_in[5];
  const float* bin  = (const float*)d_in[6];
  const float* W2   = (const float*)d_in[7];
  const float* bout = (const float*)d_in[8];
  const float* g2   = (const float*)d_in[9];
  const float* b2   = (const float*)d_in[10];
  float* ws   = (float*)d_ws;
  float* q    = ws;
  float* k    = ws + 1048576;
  float* v    = ws + 2097152;
  float* pmax = ws + 3145728;
  int*   pidx = (int*)(ws + 3407872);   // total ws use ~14.7 MB

  qkv_kernel<<<ROWS/64, 256, 0, stream>>>(x, Wq, Wkv, q, k, v);
  argmax_kernel<<<dim3(NJC, NN/256, NB), 256, 0, stream>>>(q, k, pmax, pidx);
  epilogue_kernel<<<ROWS/64, 256, 0, stream>>>(x, v, pmax, pidx, g1, b1, W1, bin,
                                               W2, bout, g2, b2, (float*)d_out);
}

// Round 3
// 120.779 us; speedup vs baseline: 1.4037x; 1.4037x over previous
//
#include <hip/hip_runtime.h>
#include <float.h>

#define NB 8
#define NN 2048
#define ROWS (NB*NN)   // 16384
#define JSPLIT 8
#define JRANGE (NN/JSPLIT)   // 256
#define CHUNK 64
#define NTILE (CHUNK/16)     // 4

typedef _Float16 half8 __attribute__((ext_vector_type(8)));
typedef _Float16 half4 __attribute__((ext_vector_type(4)));
typedef float f32x4 __attribute__((ext_vector_type(4)));

// ---------------- Kernel 1: q = x@Wq ; k,v = x@Wkv (fp32, unchanged) ------
__global__ __launch_bounds__(256) void qkv_kernel(
    const float* __restrict__ x, const float* __restrict__ Wq,
    const float* __restrict__ Wkv,
    float* __restrict__ q, float* __restrict__ k, float* __restrict__ v) {
  __shared__ float Wt[192*64];   // transposed: Wt[c][d], 48KB
  const int tid = threadIdx.x;
  for (int i = tid; i < 192*64; i += 256) {
    int c = i >> 6, d = i & 63;
    Wt[i] = (c < 64) ? Wq[d*64 + c] : Wkv[d*128 + (c - 64)];
  }
  __syncthreads();
  const int lane = tid & 63;
  const int wv = tid >> 6;
  const long rg = (long)blockIdx.x * 64 + lane;
  float4 xr[16];
  const float4* xp = (const float4*)(x + rg*64);
#pragma unroll
  for (int d4 = 0; d4 < 16; ++d4) xr[d4] = xp[d4];
  const float4* Wt4 = (const float4*)Wt;
#pragma unroll 1
  for (int cg = 0; cg < 12; ++cg) {
    const int c0 = wv*48 + cg*4;
    float a0=0.f,a1=0.f,a2=0.f,a3=0.f;
#pragma unroll
    for (int d4 = 0; d4 < 16; ++d4) {
      float4 xv = xr[d4];
      float4 w0 = Wt4[(c0+0)*16 + d4];
      float4 w1 = Wt4[(c0+1)*16 + d4];
      float4 w2 = Wt4[(c0+2)*16 + d4];
      float4 w3 = Wt4[(c0+3)*16 + d4];
      a0 = fmaf(xv.x,w0.x,a0); a1 = fmaf(xv.x,w1.x,a1); a2 = fmaf(xv.x,w2.x,a2); a3 = fmaf(xv.x,w3.x,a3);
      a0 = fmaf(xv.y,w0.y,a0); a1 = fmaf(xv.y,w1.y,a1); a2 = fmaf(xv.y,w2.y,a2); a3 = fmaf(xv.y,w3.y,a3);
      a0 = fmaf(xv.z,w0.z,a0); a1 = fmaf(xv.z,w1.z,a1); a2 = fmaf(xv.z,w2.z,a2); a3 = fmaf(xv.z,w3.z,a3);
      a0 = fmaf(xv.w,w0.w,a0); a1 = fmaf(xv.w,w1.w,a1); a2 = fmaf(xv.w,w2.w,a2); a3 = fmaf(xv.w,w3.w,a3);
    }
    float* dst; int cc;
    if (c0 < 64)       { dst = q; cc = c0; }
    else if (c0 < 128) { dst = k; cc = c0 - 64; }
    else               { dst = v; cc = c0 - 128; }
    *(float4*)(dst + rg*64 + cc) = make_float4(a0,a1,a2,a3);
  }
}

// ---------------- Kernel 2a: MFMA f16-split3 argmax filter ----------------
// S^T tiles: A = K-tile rows (j, contiguous d), B = Q rows (i, contiguous d).
// C/D (verified m89/m91): col = lane&15 = i, row = (lane>>4)*4 + reg = j.
// Tracks per-row running (max, 16-j tile id) only; exact index found in 2b.
__global__ __launch_bounds__(256,4) void argmax_mfma_kernel(
    const float* __restrict__ q, const float* __restrict__ k,
    float* __restrict__ pm, int* __restrict__ pt) {
  __shared__ _Float16 kls[2][8][CHUNK][8];   // [term][d0][j][e] = 16KB
  const int tid = threadIdx.x, lane = tid & 63, wv = tid >> 6;
  const int ib = blockIdx.x, js = blockIdx.y, b = blockIdx.z;
  const int i0 = ib*128 + wv*32;             // wave covers 32 i (2 cols of 16)
  const int lg = lane >> 4, li = lane & 15;
  // Q fragments (hi/lo), loaded once: lane holds row i0+c*16+li, d = w*32+lg*8+e
  half8 qh[2][2], ql[2][2];
#pragma unroll
  for (int c = 0; c < 2; ++c)
#pragma unroll
    for (int w = 0; w < 2; ++w) {
      const float* src = q + ((size_t)(b*NN + i0 + c*16 + li))*64 + w*32 + lg*8;
      float4 f0 = *(const float4*)src;
      float4 f1 = *(const float4*)(src+4);
      float vals[8] = {f0.x,f0.y,f0.z,f0.w,f1.x,f1.y,f1.z,f1.w};
#pragma unroll
      for (int e = 0; e < 8; ++e) {
        _Float16 h = (_Float16)vals[e];
        qh[c][w][e] = h;
        ql[c][w][e] = (_Float16)((vals[e] - (float)h) * 2048.0f);
      }
    }
  const f32x4 Z = {0.f,0.f,0.f,0.f};
  float mrun[2] = {-FLT_MAX, -FLT_MAX};
  int   trun[2] = {0, 0};
  const int j0base = js*JRANGE;
#pragma unroll 1
  for (int ch = 0; ch < JRANGE/CHUNK; ++ch) {
    const int j0 = j0base + ch*CHUNK;
    __syncthreads();
    // stage + split-convert K chunk (64 j x 64 d) into LDS
#pragma unroll
    for (int it = 0; it < 4; ++it) {
      int c = it*256 + tid;
      int j = c & 63, dq = c >> 6;           // dq = float4 index 0..15
      const float4 f = *(const float4*)(k + ((size_t)(b*NN + j0 + j))*64 + dq*4);
      float vv[4] = {f.x,f.y,f.z,f.w};
      half4 h, l;
#pragma unroll
      for (int e = 0; e < 4; ++e) {
        _Float16 hh = (_Float16)vv[e];
        h[e] = hh;
        l[e] = (_Float16)((vv[e] - (float)hh) * 2048.0f);
      }
      int d0 = dq >> 1, eo = (dq & 1)*4;
      *(half4*)&kls[0][d0][j][eo] = h;
      *(half4*)&kls[1][d0][j][eo] = l;
    }
    __syncthreads();
#pragma unroll
    for (int jt = 0; jt < NTILE; ++jt) {
      half8 akh0 = *(const half8*)&kls[0][lg  ][jt*16+li][0];
      half8 akh1 = *(const half8*)&kls[0][4+lg][jt*16+li][0];
      half8 akl0 = *(const half8*)&kls[1][lg  ][jt*16+li][0];
      half8 akl1 = *(const half8*)&kls[1][4+lg][jt*16+li][0];
      const int gtile = j0/16 + jt;          // batch-local 16-j tile id
#pragma unroll
      for (int c = 0; c < 2; ++c) {
        f32x4 hh = __builtin_amdgcn_mfma_f32_16x16x32_f16(akh0, qh[c][0], Z, 0,0,0);
        hh = __builtin_amdgcn_mfma_f32_16x16x32_f16(akh1, qh[c][1], hh, 0,0,0);
        f32x4 xx = __builtin_amdgcn_mfma_f32_16x16x32_f16(akl0, qh[c][0], Z, 0,0,0);
        xx = __builtin_amdgcn_mfma_f32_16x16x32_f16(akl1, qh[c][1], xx, 0,0,0);
        xx = __builtin_amdgcn_mfma_f32_16x16x32_f16(akh0, ql[c][0], xx, 0,0,0);
        xx = __builtin_amdgcn_mfma_f32_16x16x32_f16(akh1, ql[c][1], xx, 0,0,0);
        const float c2 = 1.0f/2048.0f;
        float s0 = fmaf(xx[0], c2, hh[0]);
        float s1 = fmaf(xx[1], c2, hh[1]);
        float s2 = fmaf(xx[2], c2, hh[2]);
        float s3 = fmaf(xx[3], c2, hh[3]);
        float tmax = fmaxf(fmaxf(s0,s1), fmaxf(s2,s3));
        if (tmax > mrun[c]) { mrun[c] = tmax; trun[c] = gtile; }  // strict >: first tile kept
      }
    }
  }
  // combine across the 4 lane-groups (lanes 16 apart share i)
#pragma unroll
  for (int c = 0; c < 2; ++c) {
#pragma unroll
    for (int mask = 16; mask <= 32; mask <<= 1) {
      float om = __shfl_xor(mrun[c], mask, 64);
      int   ot = __shfl_xor(trun[c], mask, 64);
      if (om > mrun[c] || (om == mrun[c] && ot < trun[c])) { mrun[c]=om; trun[c]=ot; }
    }
  }
  if (lane < 16) {
    size_t r = (size_t)js*ROWS + b*NN + i0 + lane;
    pm[r] = mrun[0]; pt[r] = trun[0];
  } else if (lane < 32) {
    size_t r = (size_t)js*ROWS + b*NN + i0 + 16 + (lane & 15);
    pm[r] = mrun[1]; pt[r] = trun[1];
  }
}

// ---------------- Kernel 2b: reduce splits + exact fp32 rescue of winning tile
__global__ __launch_bounds__(256) void rescue_kernel(
    const float* __restrict__ q, const float* __restrict__ k,
    const float* __restrict__ pm, const int* __restrict__ pt,
    int* __restrict__ idx) {
  const int r = blockIdx.x*256 + threadIdx.x;   // row 0..16383
  float m = -FLT_MAX; int t = 0;
#pragma unroll
  for (int js = 0; js < JSPLIT; ++js) {         // ascending + strict > = first kept
    float om = pm[(size_t)js*ROWS + r];
    int   ot = pt[(size_t)js*ROWS + r];
    if (om > m) { m = om; t = ot; }
  }
  const int b = r >> 11;
  float4 qr[16];
  const float4* qp = (const float4*)(q + (size_t)r*64);
#pragma unroll
  for (int d4 = 0; d4 < 16; ++d4) qr[d4] = qp[d4];
  float best = -FLT_MAX; int bj = 0;
#pragma unroll 2
  for (int jj = 0; jj < 16; ++jj) {
    const int j = t*16 + jj;
    const float4* kp = (const float4*)(k + ((size_t)b*NN + j)*64);
    float a0=0.f,a1=0.f,a2=0.f,a3=0.f;
#pragma unroll
    for (int d4 = 0; d4 < 16; ++d4) {
      float4 kv = kp[d4], qv = qr[d4];
      a0 = fmaf(qv.x,kv.x,a0); a1 = fmaf(qv.y,kv.y,a1);
      a2 = fmaf(qv.z,kv.z,a2); a3 = fmaf(qv.w,kv.w,a3);
    }
    float dot = (a0+a1)+(a2+a3);
    if (dot > best) { best = dot; bj = j; }     // strict >: np.argmax first-max
  }
  idx[r] = bj;
}

// ---------------- Kernel 3: gather v[idx] -> LN -> MLP -> LN -> +x (fp32 out)
__global__ __launch_bounds__(256) void epilogue_kernel(
    const float* __restrict__ x, const float* __restrict__ v,
    const int* __restrict__ idx,
    const float* __restrict__ g1, const float* __restrict__ b1,
    const float* __restrict__ W1, const float* __restrict__ bin,
    const float* __restrict__ W2, const float* __restrict__ bout,
    const float* __restrict__ g2, const float* __restrict__ b2,
    float* __restrict__ out) {
  __shared__ float WaT[64*64];
  __shared__ float WbT[64*64];
  __shared__ float mids[64*65];
  __shared__ float2 sums[64*4];
  __shared__ float vecs[6*64];
  const int tid = threadIdx.x;
  for (int i = tid; i < 4096; i += 256) {
    int m = i >> 6, d = i & 63;
    WaT[i] = W1[d*64 + m] + W1[(128+d)*64 + m];
    WbT[i] = W1[(64+d)*64 + m];
  }
  if (tid < 64) {
    vecs[tid]       = g1[tid];  vecs[64+tid]  = b1[tid];
    vecs[128+tid]   = bin[tid]; vecs[192+tid] = bout[tid];
    vecs[256+tid]   = g2[tid];  vecs[320+tid] = b2[tid];
  }
  __syncthreads();
  const int lane = tid & 63;
  const int wv = tid >> 6;
  const long rg = (long)blockIdx.x*64 + lane;
  const int idxr = idx[rg];
  float nr[64], xr[64];
  const float4* vp = (const float4*)(v + ((rg >> 11)*(long)NN + idxr)*64);
  const float4* xp = (const float4*)(x + rg*64);
#pragma unroll
  for (int d4 = 0; d4 < 16; ++d4) {
    float4 t = vp[d4];
    nr[d4*4+0]=t.x; nr[d4*4+1]=t.y; nr[d4*4+2]=t.z; nr[d4*4+3]=t.w;
    float4 u = xp[d4];
    xr[d4*4+0]=u.x; xr[d4*4+1]=u.y; xr[d4*4+2]=u.z; xr[d4*4+3]=u.w;
  }
  float s=0.f, s2=0.f;
#pragma unroll
  for (int d = 0; d < 64; ++d) { s += nr[d]; s2 += nr[d]*nr[d]; }
  float mu  = s*(1.f/64.f);
  float inv = rsqrtf(s2*(1.f/64.f) - mu*mu + 1e-5f);
#pragma unroll
  for (int d = 0; d < 64; ++d) nr[d] = (nr[d]-mu)*inv*vecs[d] + vecs[64+d];
  const float4* WaT4 = (const float4*)WaT;
  const float4* WbT4 = (const float4*)WbT;
#pragma unroll 1
  for (int mi = 0; mi < 16; ++mi) {
    const int m = wv*16 + mi;
    float a0=0.f,a1=0.f,a2=0.f,a3=0.f;
#pragma unroll
    for (int d4 = 0; d4 < 16; ++d4) {
      float4 wa = WaT4[m*16+d4];
      float4 wb = WbT4[m*16+d4];
      a0 = fmaf(nr[d4*4+0], wa.x, a0); a1 = fmaf(nr[d4*4+1], wa.y, a1);
      a2 = fmaf(nr[d4*4+2], wa.z, a2); a3 = fmaf(nr[d4*4+3], wa.w, a3);
      a0 = fmaf(xr[d4*4+0], wb.x, a0); a1 = fmaf(xr[d4*4+1], wb.y, a1);
      a2 = fmaf(xr[d4*4+2], wb.z, a2); a3 = fmaf(xr[d4*4+3], wb.w, a3);
    }
    mids[lane*65 + m] = fmaxf(vecs[128+m] + ((a0+a1)+(a2+a3)), 0.f);
  }
  __syncthreads();
  for (int i = tid; i < 4096; i += 256) WaT[i] = W2[i];
  __syncthreads();
  float rn[16];
#pragma unroll
  for (int n = 0; n < 16; ++n) rn[n] = vecs[192 + wv*16 + n];
  const float4* W2s4 = (const float4*)WaT;
#pragma unroll 1
  for (int m = 0; m < 64; ++m) {
    float mm = mids[lane*65 + m];
#pragma unroll
    for (int n4 = 0; n4 < 4; ++n4) {
      float4 w = W2s4[m*16 + wv*4 + n4];
      rn[n4*4+0] = fmaf(mm, w.x, rn[n4*4+0]);
      rn[n4*4+1] = fmaf(mm, w.y, rn[n4*4+1]);
      rn[n4*4+2] = fmaf(mm, w.z, rn[n4*4+2]);
      rn[n4*4+3] = fmaf(mm, w.w, rn[n4*4+3]);
    }
  }
  float ps=0.f, ps2=0.f;
#pragma unroll
  for (int n = 0; n < 16; ++n) { ps += rn[n]; ps2 += rn[n]*rn[n]; }
  sums[lane*4+wv] = make_float2(ps, ps2);
  __syncthreads();
  float ts=0.f, ts2=0.f;
#pragma unroll
  for (int w = 0; w < 4; ++w) { float2 p = sums[lane*4+w]; ts += p.x; ts2 += p.y; }
  float mu2  = ts*(1.f/64.f);
  float inv2 = rsqrtf(ts2*(1.f/64.f) - mu2*mu2 + 1e-5f);
  float ov[16];
#pragma unroll
  for (int n = 0; n < 16; ++n) ov[n] = (rn[n]-mu2)*inv2*vecs[256+wv*16+n] + vecs[320+wv*16+n] + xr[wv*16+n];
  float4* dst = (float4*)(out + rg*64 + wv*16);
  dst[0] = make_float4(ov[0], ov[1], ov[2], ov[3]);
  dst[1] = make_float4(ov[4], ov[5], ov[6], ov[7]);
  dst[2] = make_float4(ov[8], ov[9], ov[10], ov[11]);
  dst[3] = make_float4(ov[12],ov[13],ov[14],ov[15]);
}

extern "C" void kernel_launch(void* const* d_in, const int* in_sizes, int n_in,
                              void* d_out, int out_size, void* d_ws, size_t ws_size,
                              hipStream_t stream) {
  const float* x    = (const float*)d_in[0];
  const float* Wq   = (const float*)d_in[1];
  const float* Wkv  = (const float*)d_in[2];
  const float* g1   = (const float*)d_in[3];
  const float* b1   = (const float*)d_in[4];
  const float* W1   = (const float*)d_in[5];
  const float* bin  = (const float*)d_in[6];
  const float* W2   = (const float*)d_in[7];
  const float* bout = (const float*)d_in[8];
  const float* g2   = (const float*)d_in[9];
  const float* b2   = (const float*)d_in[10];
  float* ws   = (float*)d_ws;
  float* q    = ws;
  float* k    = ws + 1048576;
  float* v    = ws + 2097152;
  float* pm   = ws + 3145728;              // [8][16384] f32
  int*   pt   = (int*)(ws + 3276800);      // [8][16384] i32
  int*   idx  = (int*)(ws + 3407872);      // [16384] i32   (~13.7 MB total)

  qkv_kernel<<<ROWS/64, 256, 0, stream>>>(x, Wq, Wkv, q, k, v);
  argmax_mfma_kernel<<<dim3(16, JSPLIT, NB), 256, 0, stream>>>(q, k, pm, pt);
  rescue_kernel<<<ROWS/256, 256, 0, stream>>>(q, k, pm, pt, idx);
  epilogue_kernel<<<ROWS/64, 256, 0, stream>>>(x, v, idx, g1, b1, W1, bin,
                                               W2, bout, g2, b2, (float*)d_out);
}

// Round 4
// 101.712 us; speedup vs baseline: 1.6668x; 1.1875x over previous
//
#include <hip/hip_runtime.h>
#include <float.h>

#define NB 8
#define NN 2048
#define ROWS (NB*NN)   // 16384
#define JSPLIT 8
#define JRANGE (NN/JSPLIT)   // 256
#define CHUNK 64
#define NTILE (CHUNK/16)     // 4

typedef _Float16 half8 __attribute__((ext_vector_type(8)));
typedef _Float16 half4 __attribute__((ext_vector_type(4)));
typedef float f32x4 __attribute__((ext_vector_type(4)));

// ---------------- Kernel 1: q = x@Wq ; k,v = x@Wkv (fp32) ------------------
// Weights: coalesced global read -> transposed LDS write (stride 68 dwords).
// Outputs: accumulate in regs -> LDS bounce -> fully coalesced float4 stores.
__global__ __launch_bounds__(256) void qkv_kernel(
    const float* __restrict__ x, const float* __restrict__ Wq,
    const float* __restrict__ Wkv,
    float* __restrict__ q, float* __restrict__ k, float* __restrict__ v) {
  __shared__ float Wt[192*68];   // [c][d] stride 68 (52.2KB); reused as out-stage [64][196]
  const int tid = threadIdx.x;
  // Wq: i = d*64 + c  (coalesced read; scattered LDS write, 8-way conflict ok)
  for (int i = tid; i < 4096; i += 256) {
    int d = i >> 6, c = i & 63;
    Wt[c*68 + d] = Wq[i];
  }
  // Wkv: i = d*128 + c'
  for (int i = tid; i < 8192; i += 256) {
    int d = i >> 7, c = i & 127;
    Wt[(64 + c)*68 + d] = Wkv[i];
  }
  __syncthreads();
  const int lane = tid & 63;
  const int wv = tid >> 6;
  const long rg = (long)blockIdx.x * 64 + lane;
  float4 xr[16];
  const float4* xp = (const float4*)(x + rg*64);
#pragma unroll
  for (int d4 = 0; d4 < 16; ++d4) xr[d4] = xp[d4];
  const float4* Wt4 = (const float4*)Wt;
  float4 acc[12];
#pragma unroll
  for (int cg = 0; cg < 12; ++cg) {
    const int c0 = wv*48 + cg*4;
    float a0=0.f,a1=0.f,a2=0.f,a3=0.f;
#pragma unroll
    for (int d4 = 0; d4 < 16; ++d4) {
      float4 xv = xr[d4];
      float4 w0 = Wt4[(c0+0)*17 + d4];   // wave-uniform addr -> LDS broadcast
      float4 w1 = Wt4[(c0+1)*17 + d4];
      float4 w2 = Wt4[(c0+2)*17 + d4];
      float4 w3 = Wt4[(c0+3)*17 + d4];
      a0 = fmaf(xv.x,w0.x,a0); a1 = fmaf(xv.x,w1.x,a1); a2 = fmaf(xv.x,w2.x,a2); a3 = fmaf(xv.x,w3.x,a3);
      a0 = fmaf(xv.y,w0.y,a0); a1 = fmaf(xv.y,w1.y,a1); a2 = fmaf(xv.y,w2.y,a2); a3 = fmaf(xv.y,w3.y,a3);
      a0 = fmaf(xv.z,w0.z,a0); a1 = fmaf(xv.z,w1.z,a1); a2 = fmaf(xv.z,w2.z,a2); a3 = fmaf(xv.z,w3.z,a3);
      a0 = fmaf(xv.w,w0.w,a0); a1 = fmaf(xv.w,w1.w,a1); a2 = fmaf(xv.w,w2.w,a2); a3 = fmaf(xv.w,w3.w,a3);
    }
    acc[cg] = make_float4(a0,a1,a2,a3);
  }
  __syncthreads();                    // all waves done reading Wt
  // out-stage: [row=lane][col 0..191] stride 196 dwords (fits in Wt space)
#pragma unroll
  for (int cg = 0; cg < 12; ++cg)
    *(float4*)&Wt[lane*196 + wv*48 + cg*4] = acc[cg];
  __syncthreads();
  // coalesced stores: each array's block-chunk is contiguous 16KB
  const size_t rbase = (size_t)blockIdx.x * 64 * 64;
#pragma unroll
  for (int it = 0; it < 4; ++it) {
    const int off = it*1024 + tid*4;
    const int row = off >> 6, col = off & 63;
    *(float4*)(q + rbase + off) = *(const float4*)&Wt[row*196 + col];
    *(float4*)(k + rbase + off) = *(const float4*)&Wt[row*196 + 64 + col];
    *(float4*)(v + rbase + off) = *(const float4*)&Wt[row*196 + 128 + col];
  }
}

// ---------------- Kernel 2a: MFMA f16-split3 argmax filter (unchanged) -----
__global__ __launch_bounds__(256,4) void argmax_mfma_kernel(
    const float* __restrict__ q, const float* __restrict__ k,
    float* __restrict__ pm, int* __restrict__ pt) {
  __shared__ _Float16 kls[2][8][CHUNK][8];   // [term][d0][j][e] = 16KB
  const int tid = threadIdx.x, lane = tid & 63, wv = tid >> 6;
  const int ib = blockIdx.x, js = blockIdx.y, b = blockIdx.z;
  const int i0 = ib*128 + wv*32;             // wave covers 32 i (2 cols of 16)
  const int lg = lane >> 4, li = lane & 15;
  half8 qh[2][2], ql[2][2];
#pragma unroll
  for (int c = 0; c < 2; ++c)
#pragma unroll
    for (int w = 0; w < 2; ++w) {
      const float* src = q + ((size_t)(b*NN + i0 + c*16 + li))*64 + w*32 + lg*8;
      float4 f0 = *(const float4*)src;
      float4 f1 = *(const float4*)(src+4);
      float vals[8] = {f0.x,f0.y,f0.z,f0.w,f1.x,f1.y,f1.z,f1.w};
#pragma unroll
      for (int e = 0; e < 8; ++e) {
        _Float16 h = (_Float16)vals[e];
        qh[c][w][e] = h;
        ql[c][w][e] = (_Float16)((vals[e] - (float)h) * 2048.0f);
      }
    }
  const f32x4 Z = {0.f,0.f,0.f,0.f};
  float mrun[2] = {-FLT_MAX, -FLT_MAX};
  int   trun[2] = {0, 0};
  const int j0base = js*JRANGE;
#pragma unroll 1
  for (int ch = 0; ch < JRANGE/CHUNK; ++ch) {
    const int j0 = j0base + ch*CHUNK;
    __syncthreads();
#pragma unroll
    for (int it = 0; it < 4; ++it) {
      int c = it*256 + tid;
      int j = c & 63, dq = c >> 6;
      const float4 f = *(const float4*)(k + ((size_t)(b*NN + j0 + j))*64 + dq*4);
      float vv[4] = {f.x,f.y,f.z,f.w};
      half4 h, l;
#pragma unroll
      for (int e = 0; e < 4; ++e) {
        _Float16 hh = (_Float16)vv[e];
        h[e] = hh;
        l[e] = (_Float16)((vv[e] - (float)hh) * 2048.0f);
      }
      int d0 = dq >> 1, eo = (dq & 1)*4;
      *(half4*)&kls[0][d0][j][eo] = h;
      *(half4*)&kls[1][d0][j][eo] = l;
    }
    __syncthreads();
#pragma unroll
    for (int jt = 0; jt < NTILE; ++jt) {
      half8 akh0 = *(const half8*)&kls[0][lg  ][jt*16+li][0];
      half8 akh1 = *(const half8*)&kls[0][4+lg][jt*16+li][0];
      half8 akl0 = *(const half8*)&kls[1][lg  ][jt*16+li][0];
      half8 akl1 = *(const half8*)&kls[1][4+lg][jt*16+li][0];
      const int gtile = j0/16 + jt;
#pragma unroll
      for (int c = 0; c < 2; ++c) {
        f32x4 hh = __builtin_amdgcn_mfma_f32_16x16x32_f16(akh0, qh[c][0], Z, 0,0,0);
        hh = __builtin_amdgcn_mfma_f32_16x16x32_f16(akh1, qh[c][1], hh, 0,0,0);
        f32x4 xx = __builtin_amdgcn_mfma_f32_16x16x32_f16(akl0, qh[c][0], Z, 0,0,0);
        xx = __builtin_amdgcn_mfma_f32_16x16x32_f16(akl1, qh[c][1], xx, 0,0,0);
        xx = __builtin_amdgcn_mfma_f32_16x16x32_f16(akh0, ql[c][0], xx, 0,0,0);
        xx = __builtin_amdgcn_mfma_f32_16x16x32_f16(akh1, ql[c][1], xx, 0,0,0);
        const float c2 = 1.0f/2048.0f;
        float s0 = fmaf(xx[0], c2, hh[0]);
        float s1 = fmaf(xx[1], c2, hh[1]);
        float s2 = fmaf(xx[2], c2, hh[2]);
        float s3 = fmaf(xx[3], c2, hh[3]);
        float tmax = fmaxf(fmaxf(s0,s1), fmaxf(s2,s3));
        if (tmax > mrun[c]) { mrun[c] = tmax; trun[c] = gtile; }
      }
    }
  }
#pragma unroll
  for (int c = 0; c < 2; ++c) {
#pragma unroll
    for (int mask = 16; mask <= 32; mask <<= 1) {
      float om = __shfl_xor(mrun[c], mask, 64);
      int   ot = __shfl_xor(trun[c], mask, 64);
      if (om > mrun[c] || (om == mrun[c] && ot < trun[c])) { mrun[c]=om; trun[c]=ot; }
    }
  }
  if (lane < 16) {
    size_t r = (size_t)js*ROWS + b*NN + i0 + lane;
    pm[r] = mrun[0]; pt[r] = trun[0];
  } else if (lane < 32) {
    size_t r = (size_t)js*ROWS + b*NN + i0 + 16 + (lane & 15);
    pm[r] = mrun[1]; pt[r] = trun[1];
  }
}

// ---------------- Kernel 2b: reduce splits + exact fp32 rescue --------------
__global__ __launch_bounds__(64) void rescue_kernel(
    const float* __restrict__ q, const float* __restrict__ k,
    const float* __restrict__ pm, const int* __restrict__ pt,
    int* __restrict__ idx) {
  const int r = blockIdx.x*64 + threadIdx.x;
  float m = -FLT_MAX; int t = 0;
#pragma unroll
  for (int js = 0; js < JSPLIT; ++js) {
    float om = pm[(size_t)js*ROWS + r];
    int   ot = pt[(size_t)js*ROWS + r];
    if (om > m) { m = om; t = ot; }
  }
  const int b = r >> 11;
  float4 qr[16];
  const float4* qp = (const float4*)(q + (size_t)r*64);
#pragma unroll
  for (int d4 = 0; d4 < 16; ++d4) qr[d4] = qp[d4];
  float best = -FLT_MAX; int bj = 0;
#pragma unroll 2
  for (int jj = 0; jj < 16; ++jj) {
    const int j = t*16 + jj;
    const float4* kp = (const float4*)(k + ((size_t)b*NN + j)*64);
    float a0=0.f,a1=0.f,a2=0.f,a3=0.f;
#pragma unroll
    for (int d4 = 0; d4 < 16; ++d4) {
      float4 kv = kp[d4], qv = qr[d4];
      a0 = fmaf(qv.x,kv.x,a0); a1 = fmaf(qv.y,kv.y,a1);
      a2 = fmaf(qv.z,kv.z,a2); a3 = fmaf(qv.w,kv.w,a3);
    }
    float dot = (a0+a1)+(a2+a3);
    if (dot > best) { best = dot; bj = j; }
  }
  idx[r] = bj;
}

// ---------------- Kernel 3: gather v[idx] -> LN -> MLP -> LN -> +x ----------
__global__ __launch_bounds__(256) void epilogue_kernel(
    const float* __restrict__ x, const float* __restrict__ v,
    const int* __restrict__ idx,
    const float* __restrict__ g1, const float* __restrict__ b1,
    const float* __restrict__ W1, const float* __restrict__ bin,
    const float* __restrict__ W2, const float* __restrict__ bout,
    const float* __restrict__ g2, const float* __restrict__ b2,
    float* __restrict__ out) {
  __shared__ float WaT[64*68];     // [m][d] stride 68; later overlaid with W2 [m][n]
  __shared__ float WbT[64*68];     // [m][d] stride 68; later reused as out-stage [row][64]
  __shared__ float mids[64*65];
  __shared__ float2 sums[64*4];
  __shared__ float vecs[6*64];
  const int tid = threadIdx.x;
  // coalesced global reads (consecutive lanes -> consecutive m), transposed LDS write
  for (int i = tid; i < 4096; i += 256) {
    int d = i >> 6, m = i & 63;
    WaT[m*68 + d] = W1[i] + W1[8192 + i];   // W1[d][m] + W1[128+d][m]
    WbT[m*68 + d] = W1[4096 + i];           // W1[64+d][m]
  }
  if (tid < 64) {
    vecs[tid]       = g1[tid];  vecs[64+tid]  = b1[tid];
    vecs[128+tid]   = bin[tid]; vecs[192+tid] = bout[tid];
    vecs[256+tid]   = g2[tid];  vecs[320+tid] = b2[tid];
  }
  __syncthreads();
  const int lane = tid & 63;
  const int wv = tid >> 6;
  const long rg = (long)blockIdx.x*64 + lane;
  const int idxr = idx[rg];
  float nr[64], xr[64];
  const float4* vp = (const float4*)(v + ((rg >> 11)*(long)NN + idxr)*64);
  const float4* xp = (const float4*)(x + rg*64);
#pragma unroll
  for (int d4 = 0; d4 < 16; ++d4) {
    float4 t = vp[d4];
    nr[d4*4+0]=t.x; nr[d4*4+1]=t.y; nr[d4*4+2]=t.z; nr[d4*4+3]=t.w;
    float4 u = xp[d4];
    xr[d4*4+0]=u.x; xr[d4*4+1]=u.y; xr[d4*4+2]=u.z; xr[d4*4+3]=u.w;
  }
  float s=0.f, s2=0.f;
#pragma unroll
  for (int d = 0; d < 64; ++d) { s += nr[d]; s2 += nr[d]*nr[d]; }
  float mu  = s*(1.f/64.f);
  float inv = rsqrtf(s2*(1.f/64.f) - mu*mu + 1e-5f);
#pragma unroll
  for (int d = 0; d < 64; ++d) nr[d] = (nr[d]-mu)*inv*vecs[d] + vecs[64+d];
  const float4* WaT4 = (const float4*)WaT;
  const float4* WbT4 = (const float4*)WbT;
#pragma unroll 1
  for (int mi = 0; mi < 16; ++mi) {
    const int m = wv*16 + mi;
    float a0=0.f,a1=0.f,a2=0.f,a3=0.f;
#pragma unroll
    for (int d4 = 0; d4 < 16; ++d4) {
      float4 wa = WaT4[m*17+d4];    // wave-uniform -> broadcast
      float4 wb = WbT4[m*17+d4];
      a0 = fmaf(nr[d4*4+0], wa.x, a0); a1 = fmaf(nr[d4*4+1], wa.y, a1);
      a2 = fmaf(nr[d4*4+2], wa.z, a2); a3 = fmaf(nr[d4*4+3], wa.w, a3);
      a0 = fmaf(xr[d4*4+0], wb.x, a0); a1 = fmaf(xr[d4*4+1], wb.y, a1);
      a2 = fmaf(xr[d4*4+2], wb.z, a2); a3 = fmaf(xr[d4*4+3], wb.w, a3);
    }
    mids[lane*65 + m] = fmaxf(vecs[128+m] + ((a0+a1)+(a2+a3)), 0.f);
  }
  __syncthreads();
  // overlay W2 into WaT rows (coalesced read; write banks conflict-free)
  for (int i = tid; i < 4096; i += 256) WaT[(i>>6)*68 + (i&63)] = W2[i];
  __syncthreads();
  float rn[16];
#pragma unroll
  for (int n = 0; n < 16; ++n) rn[n] = vecs[192 + wv*16 + n];
#pragma unroll 1
  for (int m = 0; m < 64; ++m) {
    float mm = mids[lane*65 + m];
#pragma unroll
    for (int n4 = 0; n4 < 4; ++n4) {
      float4 w = WaT4[m*17 + wv*4 + n4];
      rn[n4*4+0] = fmaf(mm, w.x, rn[n4*4+0]);
      rn[n4*4+1] = fmaf(mm, w.y, rn[n4*4+1]);
      rn[n4*4+2] = fmaf(mm, w.z, rn[n4*4+2]);
      rn[n4*4+3] = fmaf(mm, w.w, rn[n4*4+3]);
    }
  }
  float ps=0.f, ps2=0.f;
#pragma unroll
  for (int n = 0; n < 16; ++n) { ps += rn[n]; ps2 += rn[n]*rn[n]; }
  sums[lane*4+wv] = make_float2(ps, ps2);
  __syncthreads();
  float ts=0.f, ts2=0.f;
#pragma unroll
  for (int w = 0; w < 4; ++w) { float2 p = sums[lane*4+w]; ts += p.x; ts2 += p.y; }
  float mu2  = ts*(1.f/64.f);
  float inv2 = rsqrtf(ts2*(1.f/64.f) - mu2*mu2 + 1e-5f);
  float ov[16];
#pragma unroll
  for (int n = 0; n < 16; ++n) ov[n] = (rn[n]-mu2)*inv2*vecs[256+wv*16+n] + vecs[320+wv*16+n] + xr[wv*16+n];
  // out-stage into WbT region (dead since mid-loop): [row=lane][col] stride 68
#pragma unroll
  for (int n4 = 0; n4 < 4; ++n4)
    *(float4*)&WbT[lane*68 + wv*16 + n4*4] = make_float4(ov[n4*4],ov[n4*4+1],ov[n4*4+2],ov[n4*4+3]);
  __syncthreads();
  // coalesced store: block's 16KB contiguous output chunk
  const size_t obase = (size_t)blockIdx.x * 64 * 64;
#pragma unroll
  for (int it = 0; it < 4; ++it) {
    const int off = it*1024 + tid*4;
    const int row = off >> 6, col = off & 63;
    *(float4*)(out + obase + off) = *(const float4*)&WbT[row*68 + col];
  }
}

extern "C" void kernel_launch(void* const* d_in, const int* in_sizes, int n_in,
                              void* d_out, int out_size, void* d_ws, size_t ws_size,
                              hipStream_t stream) {
  const float* x    = (const float*)d_in[0];
  const float* Wq   = (const float*)d_in[1];
  const float* Wkv  = (const float*)d_in[2];
  const float* g1   = (const float*)d_in[3];
  const float* b1   = (const float*)d_in[4];
  const float* W1   = (const float*)d_in[5];
  const float* bin  = (const float*)d_in[6];
  const float* W2   = (const float*)d_in[7];
  const float* bout = (const float*)d_in[8];
  const float* g2   = (const float*)d_in[9];
  const float* b2   = (const float*)d_in[10];
  float* ws   = (float*)d_ws;
  float* q    = ws;
  float* k    = ws + 1048576;
  float* v    = ws + 2097152;
  float* pm   = ws + 3145728;              // [8][16384] f32
  int*   pt   = (int*)(ws + 3276800);      // [8][16384] i32
  int*   idx  = (int*)(ws + 3407872);      // [16384] i32

  qkv_kernel<<<ROWS/64, 256, 0, stream>>>(x, Wq, Wkv, q, k, v);
  argmax_mfma_kernel<<<dim3(16, JSPLIT, NB), 256, 0, stream>>>(q, k, pm, pt);
  rescue_kernel<<<ROWS/64, 64, 0, stream>>>(q, k, pm, pt, idx);
  epilogue_kernel<<<ROWS/64, 256, 0, stream>>>(x, v, idx, g1, b1, W1, bin,
                                               W2, bout, g2, b2, (float*)d_out);
}

// Round 5
// 88.259 us; speedup vs baseline: 1.9209x; 1.1524x over previous
//
#include <hip/hip_runtime.h>
#include <float.h>

#define NB 8
#define NN 2048
#define ROWS (NB*NN)   // 16384
#define JSPLIT 8
#define JRANGE (NN/JSPLIT)   // 256
#define CHUNK 64
#define NTILE (CHUNK/16)     // 4

typedef _Float16 half8 __attribute__((ext_vector_type(8)));
typedef _Float16 half4 __attribute__((ext_vector_type(4)));
typedef float f32x4 __attribute__((ext_vector_type(4)));

// ---------------- Kernel 1: q,k,v = x @ [Wq|Wkv] via f16 split-3 MFMA ------
// A = W columns (c), B = x rows (r). D: col=lane&15 = r, row=(lg*4+reg) = c.
// Each wave: 3 col-tiles x 2 row-tiles. LDS bounce -> coalesced stores.
__global__ __launch_bounds__(256) void qkv_kernel(
    const float* __restrict__ x, const float* __restrict__ Wq,
    const float* __restrict__ Wkv,
    float* __restrict__ q, float* __restrict__ k, float* __restrict__ v) {
  __shared__ float stage[32*196];   // [r_local][c 0..191], 25KB
  const int tid = threadIdx.x, lane = tid & 63, wv = tid >> 6;
  const int li = lane & 15, lg = lane >> 4;
  const size_t r0 = (size_t)blockIdx.x * 32;
  // x fragments: lane holds x[r0+rt*16+li][kh*32+lg*8+e]
  half8 xh[2][2], xl[2][2];
#pragma unroll
  for (int rt = 0; rt < 2; ++rt)
#pragma unroll
    for (int kh = 0; kh < 2; ++kh) {
      const float* src = x + (r0 + rt*16 + li)*64 + kh*32 + lg*8;
      float4 f0 = *(const float4*)src;
      float4 f1 = *(const float4*)(src+4);
      float vals[8] = {f0.x,f0.y,f0.z,f0.w,f1.x,f1.y,f1.z,f1.w};
#pragma unroll
      for (int e = 0; e < 8; ++e) {
        _Float16 h = (_Float16)vals[e];
        xh[rt][kh][e] = h;
        xl[rt][kh][e] = (_Float16)((vals[e] - (float)h) * 2048.0f);
      }
    }
  // W fragments: lane holds W[kh*32+lg*8+e][ct*16+li], ct = wv*3+ci
  half8 wh[3][2], wl[3][2];
#pragma unroll
  for (int ci = 0; ci < 3; ++ci) {
    const int ct = wv*3 + ci;
    const int c  = ct*16 + li;
    const float* base; int strideW;
    if (ct < 4) { base = Wq + c; strideW = 64; }
    else        { base = Wkv + (c - 64); strideW = 128; }
#pragma unroll
    for (int kh = 0; kh < 2; ++kh) {
      const int kbase = kh*32 + lg*8;
#pragma unroll
      for (int e = 0; e < 8; ++e) {
        float val = base[(size_t)(kbase + e) * strideW];
        _Float16 h = (_Float16)val;
        wh[ci][kh][e] = h;
        wl[ci][kh][e] = (_Float16)((val - (float)h) * 2048.0f);
      }
    }
  }
  const f32x4 Z = {0.f,0.f,0.f,0.f};
#pragma unroll
  for (int rt = 0; rt < 2; ++rt)
#pragma unroll
    for (int ci = 0; ci < 3; ++ci) {
      f32x4 hh = __builtin_amdgcn_mfma_f32_16x16x32_f16(wh[ci][0], xh[rt][0], Z, 0,0,0);
      hh = __builtin_amdgcn_mfma_f32_16x16x32_f16(wh[ci][1], xh[rt][1], hh, 0,0,0);
      f32x4 xx = __builtin_amdgcn_mfma_f32_16x16x32_f16(wl[ci][0], xh[rt][0], Z, 0,0,0);
      xx = __builtin_amdgcn_mfma_f32_16x16x32_f16(wl[ci][1], xh[rt][1], xx, 0,0,0);
      xx = __builtin_amdgcn_mfma_f32_16x16x32_f16(wh[ci][0], xl[rt][0], xx, 0,0,0);
      xx = __builtin_amdgcn_mfma_f32_16x16x32_f16(wh[ci][1], xl[rt][1], xx, 0,0,0);
      const float c2 = 1.0f/2048.0f;
      float s0 = fmaf(xx[0], c2, hh[0]);
      float s1 = fmaf(xx[1], c2, hh[1]);
      float s2 = fmaf(xx[2], c2, hh[2]);
      float s3 = fmaf(xx[3], c2, hh[3]);
      // lane holds out[r0+rt*16+li][(wv*3+ci)*16 + lg*4 + 0..3]
      *(float4*)&stage[(rt*16 + li)*196 + (wv*3+ci)*16 + lg*4] = make_float4(s0,s1,s2,s3);
    }
  __syncthreads();
  // coalesced stores: each array's block chunk = 32 rows x 64 cols contiguous
  const size_t obase = r0 * 64;
#pragma unroll
  for (int it = 0; it < 2; ++it) {
    const int off = it*1024 + tid*4;
    const int row = off >> 6, col = off & 63;
    *(float4*)(q + obase + off) = *(const float4*)&stage[row*196 + col];
    *(float4*)(k + obase + off) = *(const float4*)&stage[row*196 + 64 + col];
    *(float4*)(v + obase + off) = *(const float4*)&stage[row*196 + 128 + col];
  }
}

// ---------------- Kernel 2a: MFMA f16-split3 argmax filter (unchanged) -----
__global__ __launch_bounds__(256,4) void argmax_mfma_kernel(
    const float* __restrict__ q, const float* __restrict__ k,
    float* __restrict__ pm, int* __restrict__ pt) {
  __shared__ _Float16 kls[2][8][CHUNK][8];   // [term][d0][j][e] = 16KB
  const int tid = threadIdx.x, lane = tid & 63, wv = tid >> 6;
  const int ib = blockIdx.x, js = blockIdx.y, b = blockIdx.z;
  const int i0 = ib*128 + wv*32;             // wave covers 32 i (2 cols of 16)
  const int lg = lane >> 4, li = lane & 15;
  half8 qh[2][2], ql[2][2];
#pragma unroll
  for (int c = 0; c < 2; ++c)
#pragma unroll
    for (int w = 0; w < 2; ++w) {
      const float* src = q + ((size_t)(b*NN + i0 + c*16 + li))*64 + w*32 + lg*8;
      float4 f0 = *(const float4*)src;
      float4 f1 = *(const float4*)(src+4);
      float vals[8] = {f0.x,f0.y,f0.z,f0.w,f1.x,f1.y,f1.z,f1.w};
#pragma unroll
      for (int e = 0; e < 8; ++e) {
        _Float16 h = (_Float16)vals[e];
        qh[c][w][e] = h;
        ql[c][w][e] = (_Float16)((vals[e] - (float)h) * 2048.0f);
      }
    }
  const f32x4 Z = {0.f,0.f,0.f,0.f};
  float mrun[2] = {-FLT_MAX, -FLT_MAX};
  int   trun[2] = {0, 0};
  const int j0base = js*JRANGE;
#pragma unroll 1
  for (int ch = 0; ch < JRANGE/CHUNK; ++ch) {
    const int j0 = j0base + ch*CHUNK;
    __syncthreads();
#pragma unroll
    for (int it = 0; it < 4; ++it) {
      int c = it*256 + tid;
      int j = c & 63, dq = c >> 6;
      const float4 f = *(const float4*)(k + ((size_t)(b*NN + j0 + j))*64 + dq*4);
      float vv[4] = {f.x,f.y,f.z,f.w};
      half4 h, l;
#pragma unroll
      for (int e = 0; e < 4; ++e) {
        _Float16 hh = (_Float16)vv[e];
        h[e] = hh;
        l[e] = (_Float16)((vv[e] - (float)hh) * 2048.0f);
      }
      int d0 = dq >> 1, eo = (dq & 1)*4;
      *(half4*)&kls[0][d0][j][eo] = h;
      *(half4*)&kls[1][d0][j][eo] = l;
    }
    __syncthreads();
#pragma unroll
    for (int jt = 0; jt < NTILE; ++jt) {
      half8 akh0 = *(const half8*)&kls[0][lg  ][jt*16+li][0];
      half8 akh1 = *(const half8*)&kls[0][4+lg][jt*16+li][0];
      half8 akl0 = *(const half8*)&kls[1][lg  ][jt*16+li][0];
      half8 akl1 = *(const half8*)&kls[1][4+lg][jt*16+li][0];
      const int gtile = j0/16 + jt;
#pragma unroll
      for (int c = 0; c < 2; ++c) {
        f32x4 hh = __builtin_amdgcn_mfma_f32_16x16x32_f16(akh0, qh[c][0], Z, 0,0,0);
        hh = __builtin_amdgcn_mfma_f32_16x16x32_f16(akh1, qh[c][1], hh, 0,0,0);
        f32x4 xx = __builtin_amdgcn_mfma_f32_16x16x32_f16(akl0, qh[c][0], Z, 0,0,0);
        xx = __builtin_amdgcn_mfma_f32_16x16x32_f16(akl1, qh[c][1], xx, 0,0,0);
        xx = __builtin_amdgcn_mfma_f32_16x16x32_f16(akh0, ql[c][0], xx, 0,0,0);
        xx = __builtin_amdgcn_mfma_f32_16x16x32_f16(akh1, ql[c][1], xx, 0,0,0);
        const float c2 = 1.0f/2048.0f;
        float s0 = fmaf(xx[0], c2, hh[0]);
        float s1 = fmaf(xx[1], c2, hh[1]);
        float s2 = fmaf(xx[2], c2, hh[2]);
        float s3 = fmaf(xx[3], c2, hh[3]);
        float tmax = fmaxf(fmaxf(s0,s1), fmaxf(s2,s3));
        if (tmax > mrun[c]) { mrun[c] = tmax; trun[c] = gtile; }
      }
    }
  }
#pragma unroll
  for (int c = 0; c < 2; ++c) {
#pragma unroll
    for (int mask = 16; mask <= 32; mask <<= 1) {
      float om = __shfl_xor(mrun[c], mask, 64);
      int   ot = __shfl_xor(trun[c], mask, 64);
      if (om > mrun[c] || (om == mrun[c] && ot < trun[c])) { mrun[c]=om; trun[c]=ot; }
    }
  }
  if (lane < 16) {
    size_t r = (size_t)js*ROWS + b*NN + i0 + lane;
    pm[r] = mrun[0]; pt[r] = trun[0];
  } else if (lane < 32) {
    size_t r = (size_t)js*ROWS + b*NN + i0 + 16 + (lane & 15);
    pm[r] = mrun[1]; pt[r] = trun[1];
  }
}

// ---------------- Kernel 2b: reduce splits + exact fp32 rescue --------------
__global__ __launch_bounds__(64) void rescue_kernel(
    const float* __restrict__ q, const float* __restrict__ k,
    const float* __restrict__ pm, const int* __restrict__ pt,
    int* __restrict__ idx) {
  const int r = blockIdx.x*64 + threadIdx.x;
  float m = -FLT_MAX; int t = 0;
#pragma unroll
  for (int js = 0; js < JSPLIT; ++js) {
    float om = pm[(size_t)js*ROWS + r];
    int   ot = pt[(size_t)js*ROWS + r];
    if (om > m) { m = om; t = ot; }
  }
  const int b = r >> 11;
  float4 qr[16];
  const float4* qp = (const float4*)(q + (size_t)r*64);
#pragma unroll
  for (int d4 = 0; d4 < 16; ++d4) qr[d4] = qp[d4];
  float best = -FLT_MAX; int bj = 0;
#pragma unroll 2
  for (int jj = 0; jj < 16; ++jj) {
    const int j = t*16 + jj;
    const float4* kp = (const float4*)(k + ((size_t)b*NN + j)*64);
    float a0=0.f,a1=0.f,a2=0.f,a3=0.f;
#pragma unroll
    for (int d4 = 0; d4 < 16; ++d4) {
      float4 kv = kp[d4], qv = qr[d4];
      a0 = fmaf(qv.x,kv.x,a0); a1 = fmaf(qv.y,kv.y,a1);
      a2 = fmaf(qv.z,kv.z,a2); a3 = fmaf(qv.w,kv.w,a3);
    }
    float dot = (a0+a1)+(a2+a3);
    if (dot > best) { best = dot; bj = j; }
  }
  idx[r] = bj;
}

// ---------------- Kernel 3: gather v[idx] -> LN -> MLP -> LN -> +x ----------
__global__ __launch_bounds__(256) void epilogue_kernel(
    const float* __restrict__ x, const float* __restrict__ v,
    const int* __restrict__ idx,
    const float* __restrict__ g1, const float* __restrict__ b1,
    const float* __restrict__ W1, const float* __restrict__ bin,
    const float* __restrict__ W2, const float* __restrict__ bout,
    const float* __restrict__ g2, const float* __restrict__ b2,
    float* __restrict__ out) {
  __shared__ float WaT[64*68];     // [m][d] stride 68; later overlaid with W2 [m][n]
  __shared__ float WbT[64*68];     // [m][d] stride 68; later reused as out-stage
  __shared__ float mids[64*65];
  __shared__ float2 sums[64*4];
  __shared__ float vecs[6*64];
  const int tid = threadIdx.x;
  for (int i = tid; i < 4096; i += 256) {
    int d = i >> 6, m = i & 63;
    WaT[m*68 + d] = W1[i] + W1[8192 + i];   // W1[d][m] + W1[128+d][m]
    WbT[m*68 + d] = W1[4096 + i];           // W1[64+d][m]
  }
  if (tid < 64) {
    vecs[tid]       = g1[tid];  vecs[64+tid]  = b1[tid];
    vecs[128+tid]   = bin[tid]; vecs[192+tid] = bout[tid];
    vecs[256+tid]   = g2[tid];  vecs[320+tid] = b2[tid];
  }
  __syncthreads();
  const int lane = tid & 63;
  const int wv = tid >> 6;
  const long rg = (long)blockIdx.x*64 + lane;
  const int idxr = idx[rg];
  float nr[64], xr[64];
  const float4* vp = (const float4*)(v + ((rg >> 11)*(long)NN + idxr)*64);
  const float4* xp = (const float4*)(x + rg*64);
#pragma unroll
  for (int d4 = 0; d4 < 16; ++d4) {
    float4 t = vp[d4];
    nr[d4*4+0]=t.x; nr[d4*4+1]=t.y; nr[d4*4+2]=t.z; nr[d4*4+3]=t.w;
    float4 u = xp[d4];
    xr[d4*4+0]=u.x; xr[d4*4+1]=u.y; xr[d4*4+2]=u.z; xr[d4*4+3]=u.w;
  }
  float s=0.f, s2=0.f;
#pragma unroll
  for (int d = 0; d < 64; ++d) { s += nr[d]; s2 += nr[d]*nr[d]; }
  float mu  = s*(1.f/64.f);
  float inv = rsqrtf(s2*(1.f/64.f) - mu*mu + 1e-5f);
#pragma unroll
  for (int d = 0; d < 64; ++d) nr[d] = (nr[d]-mu)*inv*vecs[d] + vecs[64+d];
  const float4* WaT4 = (const float4*)WaT;
  const float4* WbT4 = (const float4*)WbT;
#pragma unroll 1
  for (int mi = 0; mi < 16; ++mi) {
    const int m = wv*16 + mi;
    float a0=0.f,a1=0.f,a2=0.f,a3=0.f;
#pragma unroll
    for (int d4 = 0; d4 < 16; ++d4) {
      float4 wa = WaT4[m*17+d4];    // wave-uniform -> broadcast
      float4 wb = WbT4[m*17+d4];
      a0 = fmaf(nr[d4*4+0], wa.x, a0); a1 = fmaf(nr[d4*4+1], wa.y, a1);
      a2 = fmaf(nr[d4*4+2], wa.z, a2); a3 = fmaf(nr[d4*4+3], wa.w, a3);
      a0 = fmaf(xr[d4*4+0], wb.x, a0); a1 = fmaf(xr[d4*4+1], wb.y, a1);
      a2 = fmaf(xr[d4*4+2], wb.z, a2); a3 = fmaf(xr[d4*4+3], wb.w, a3);
    }
    mids[lane*65 + m] = fmaxf(vecs[128+m] + ((a0+a1)+(a2+a3)), 0.f);
  }
  __syncthreads();
  for (int i = tid; i < 4096; i += 256) WaT[(i>>6)*68 + (i&63)] = W2[i];
  __syncthreads();
  float rn[16];
#pragma unroll
  for (int n = 0; n < 16; ++n) rn[n] = vecs[192 + wv*16 + n];
#pragma unroll 1
  for (int m = 0; m < 64; ++m) {
    float mm = mids[lane*65 + m];
#pragma unroll
    for (int n4 = 0; n4 < 4; ++n4) {
      float4 w = WaT4[m*17 + wv*4 + n4];
      rn[n4*4+0] = fmaf(mm, w.x, rn[n4*4+0]);
      rn[n4*4+1] = fmaf(mm, w.y, rn[n4*4+1]);
      rn[n4*4+2] = fmaf(mm, w.z, rn[n4*4+2]);
      rn[n4*4+3] = fmaf(mm, w.w, rn[n4*4+3]);
    }
  }
  float ps=0.f, ps2=0.f;
#pragma unroll
  for (int n = 0; n < 16; ++n) { ps += rn[n]; ps2 += rn[n]*rn[n]; }
  sums[lane*4+wv] = make_float2(ps, ps2);
  __syncthreads();
  float ts=0.f, ts2=0.f;
#pragma unroll
  for (int w = 0; w < 4; ++w) { float2 p = sums[lane*4+w]; ts += p.x; ts2 += p.y; }
  float mu2  = ts*(1.f/64.f);
  float inv2 = rsqrtf(ts2*(1.f/64.f) - mu2*mu2 + 1e-5f);
  float ov[16];
#pragma unroll
  for (int n = 0; n < 16; ++n) ov[n] = (rn[n]-mu2)*inv2*vecs[256+wv*16+n] + vecs[320+wv*16+n] + xr[wv*16+n];
#pragma unroll
  for (int n4 = 0; n4 < 4; ++n4)
    *(float4*)&WbT[lane*68 + wv*16 + n4*4] = make_float4(ov[n4*4],ov[n4*4+1],ov[n4*4+2],ov[n4*4+3]);
  __syncthreads();
  const size_t obase = (size_t)blockIdx.x * 64 * 64;
#pragma unroll
  for (int it = 0; it < 4; ++it) {
    const int off = it*1024 + tid*4;
    const int row = off >> 6, col = off & 63;
    *(float4*)(out + obase + off) = *(const float4*)&WbT[row*68 + col];
  }
}

extern "C" void kernel_launch(void* const* d_in, const int* in_sizes, int n_in,
                              void* d_out, int out_size, void* d_ws, size_t ws_size,
                              hipStream_t stream) {
  const float* x    = (const float*)d_in[0];
  const float* Wq   = (const float*)d_in[1];
  const float* Wkv  = (const float*)d_in[2];
  const float* g1   = (const float*)d_in[3];
  const float* b1   = (const float*)d_in[4];
  const float* W1   = (const float*)d_in[5];
  const float* bin  = (const float*)d_in[6];
  const float* W2   = (const float*)d_in[7];
  const float* bout = (const float*)d_in[8];
  const float* g2   = (const float*)d_in[9];
  const float* b2   = (const float*)d_in[10];
  float* ws   = (float*)d_ws;
  float* q    = ws;
  float* k    = ws + 1048576;
  float* v    = ws + 2097152;
  float* pm   = ws + 3145728;              // [8][16384] f32
  int*   pt   = (int*)(ws + 3276800);      // [8][16384] i32
  int*   idx  = (int*)(ws + 3407872);      // [16384] i32

  qkv_kernel<<<ROWS/32, 256, 0, stream>>>(x, Wq, Wkv, q, k, v);
  argmax_mfma_kernel<<<dim3(16, JSPLIT, NB), 256, 0, stream>>>(q, k, pm, pt);
  rescue_kernel<<<ROWS/64, 64, 0, stream>>>(q, k, pm, pt, idx);
  epilogue_kernel<<<ROWS/64, 256, 0, stream>>>(x, v, idx, g1, b1, W1, bin,
                                               W2, bout, g2, b2, (float*)d_out);
}

// Round 6
// 70.163 us; speedup vs baseline: 2.4163x; 1.2579x over previous
//
#include <hip/hip_runtime.h>
#include <float.h>

#define NB 8
#define NN 2048
#define ROWS (NB*NN)   // 16384
#define JSPLIT 8
#define JRANGE (NN/JSPLIT)   // 256
#define CHUNK 64
#define NTILE (CHUNK/16)     // 4

typedef _Float16 half8 __attribute__((ext_vector_type(8)));
typedef _Float16 half4 __attribute__((ext_vector_type(4)));
typedef float f32x4 __attribute__((ext_vector_type(4)));

// ---------------- Kernel 1: q,k,v = x @ [Wq|Wkv] via f16 split-3 MFMA ------
__global__ __launch_bounds__(256) void qkv_kernel(
    const float* __restrict__ x, const float* __restrict__ Wq,
    const float* __restrict__ Wkv,
    float* __restrict__ q, float* __restrict__ k, float* __restrict__ v) {
  __shared__ float stage[32*196];   // [r_local][c 0..191], 25KB
  const int tid = threadIdx.x, lane = tid & 63, wv = tid >> 6;
  const int li = lane & 15, lg = lane >> 4;
  const size_t r0 = (size_t)blockIdx.x * 32;
  half8 xh[2][2], xl[2][2];
#pragma unroll
  for (int rt = 0; rt < 2; ++rt)
#pragma unroll
    for (int kh = 0; kh < 2; ++kh) {
      const float* src = x + (r0 + rt*16 + li)*64 + kh*32 + lg*8;
      float4 f0 = *(const float4*)src;
      float4 f1 = *(const float4*)(src+4);
      float vals[8] = {f0.x,f0.y,f0.z,f0.w,f1.x,f1.y,f1.z,f1.w};
#pragma unroll
      for (int e = 0; e < 8; ++e) {
        _Float16 h = (_Float16)vals[e];
        xh[rt][kh][e] = h;
        xl[rt][kh][e] = (_Float16)((vals[e] - (float)h) * 2048.0f);
      }
    }
  half8 wh[3][2], wl[3][2];
#pragma unroll
  for (int ci = 0; ci < 3; ++ci) {
    const int ct = wv*3 + ci;
    const int c  = ct*16 + li;
    const float* base; int strideW;
    if (ct < 4) { base = Wq + c; strideW = 64; }
    else        { base = Wkv + (c - 64); strideW = 128; }
#pragma unroll
    for (int kh = 0; kh < 2; ++kh) {
      const int kbase = kh*32 + lg*8;
#pragma unroll
      for (int e = 0; e < 8; ++e) {
        float val = base[(size_t)(kbase + e) * strideW];
        _Float16 h = (_Float16)val;
        wh[ci][kh][e] = h;
        wl[ci][kh][e] = (_Float16)((val - (float)h) * 2048.0f);
      }
    }
  }
  const f32x4 Z = {0.f,0.f,0.f,0.f};
#pragma unroll
  for (int rt = 0; rt < 2; ++rt)
#pragma unroll
    for (int ci = 0; ci < 3; ++ci) {
      f32x4 hh = __builtin_amdgcn_mfma_f32_16x16x32_f16(wh[ci][0], xh[rt][0], Z, 0,0,0);
      hh = __builtin_amdgcn_mfma_f32_16x16x32_f16(wh[ci][1], xh[rt][1], hh, 0,0,0);
      f32x4 xx = __builtin_amdgcn_mfma_f32_16x16x32_f16(wl[ci][0], xh[rt][0], Z, 0,0,0);
      xx = __builtin_amdgcn_mfma_f32_16x16x32_f16(wl[ci][1], xh[rt][1], xx, 0,0,0);
      xx = __builtin_amdgcn_mfma_f32_16x16x32_f16(wh[ci][0], xl[rt][0], xx, 0,0,0);
      xx = __builtin_amdgcn_mfma_f32_16x16x32_f16(wh[ci][1], xl[rt][1], xx, 0,0,0);
      const float c2 = 1.0f/2048.0f;
      float s0 = fmaf(xx[0], c2, hh[0]);
      float s1 = fmaf(xx[1], c2, hh[1]);
      float s2 = fmaf(xx[2], c2, hh[2]);
      float s3 = fmaf(xx[3], c2, hh[3]);
      *(float4*)&stage[(rt*16 + li)*196 + (wv*3+ci)*16 + lg*4] = make_float4(s0,s1,s2,s3);
    }
  __syncthreads();
  const size_t obase = r0 * 64;
#pragma unroll
  for (int it = 0; it < 2; ++it) {
    const int off = it*1024 + tid*4;
    const int row = off >> 6, col = off & 63;
    *(float4*)(q + obase + off) = *(const float4*)&stage[row*196 + col];
    *(float4*)(k + obase + off) = *(const float4*)&stage[row*196 + 64 + col];
    *(float4*)(v + obase + off) = *(const float4*)&stage[row*196 + 128 + col];
  }
}

// ---------------- Kernel 2a: MFMA f16-split3 argmax filter (unchanged) -----
__global__ __launch_bounds__(256,4) void argmax_mfma_kernel(
    const float* __restrict__ q, const float* __restrict__ k,
    float* __restrict__ pm, int* __restrict__ pt) {
  __shared__ _Float16 kls[2][8][CHUNK][8];   // [term][d0][j][e] = 16KB
  const int tid = threadIdx.x, lane = tid & 63, wv = tid >> 6;
  const int ib = blockIdx.x, js = blockIdx.y, b = blockIdx.z;
  const int i0 = ib*128 + wv*32;
  const int lg = lane >> 4, li = lane & 15;
  half8 qh[2][2], ql[2][2];
#pragma unroll
  for (int c = 0; c < 2; ++c)
#pragma unroll
    for (int w = 0; w < 2; ++w) {
      const float* src = q + ((size_t)(b*NN + i0 + c*16 + li))*64 + w*32 + lg*8;
      float4 f0 = *(const float4*)src;
      float4 f1 = *(const float4*)(src+4);
      float vals[8] = {f0.x,f0.y,f0.z,f0.w,f1.x,f1.y,f1.z,f1.w};
#pragma unroll
      for (int e = 0; e < 8; ++e) {
        _Float16 h = (_Float16)vals[e];
        qh[c][w][e] = h;
        ql[c][w][e] = (_Float16)((vals[e] - (float)h) * 2048.0f);
      }
    }
  const f32x4 Z = {0.f,0.f,0.f,0.f};
  float mrun[2] = {-FLT_MAX, -FLT_MAX};
  int   trun[2] = {0, 0};
  const int j0base = js*JRANGE;
#pragma unroll 1
  for (int ch = 0; ch < JRANGE/CHUNK; ++ch) {
    const int j0 = j0base + ch*CHUNK;
    __syncthreads();
#pragma unroll
    for (int it = 0; it < 4; ++it) {
      int c = it*256 + tid;
      int j = c & 63, dq = c >> 6;
      const float4 f = *(const float4*)(k + ((size_t)(b*NN + j0 + j))*64 + dq*4);
      float vv[4] = {f.x,f.y,f.z,f.w};
      half4 h, l;
#pragma unroll
      for (int e = 0; e < 4; ++e) {
        _Float16 hh = (_Float16)vv[e];
        h[e] = hh;
        l[e] = (_Float16)((vv[e] - (float)hh) * 2048.0f);
      }
      int d0 = dq >> 1, eo = (dq & 1)*4;
      *(half4*)&kls[0][d0][j][eo] = h;
      *(half4*)&kls[1][d0][j][eo] = l;
    }
    __syncthreads();
#pragma unroll
    for (int jt = 0; jt < NTILE; ++jt) {
      half8 akh0 = *(const half8*)&kls[0][lg  ][jt*16+li][0];
      half8 akh1 = *(const half8*)&kls[0][4+lg][jt*16+li][0];
      half8 akl0 = *(const half8*)&kls[1][lg  ][jt*16+li][0];
      half8 akl1 = *(const half8*)&kls[1][4+lg][jt*16+li][0];
      const int gtile = j0/16 + jt;
#pragma unroll
      for (int c = 0; c < 2; ++c) {
        f32x4 hh = __builtin_amdgcn_mfma_f32_16x16x32_f16(akh0, qh[c][0], Z, 0,0,0);
        hh = __builtin_amdgcn_mfma_f32_16x16x32_f16(akh1, qh[c][1], hh, 0,0,0);
        f32x4 xx = __builtin_amdgcn_mfma_f32_16x16x32_f16(akl0, qh[c][0], Z, 0,0,0);
        xx = __builtin_amdgcn_mfma_f32_16x16x32_f16(akl1, qh[c][1], xx, 0,0,0);
        xx = __builtin_amdgcn_mfma_f32_16x16x32_f16(akh0, ql[c][0], xx, 0,0,0);
        xx = __builtin_amdgcn_mfma_f32_16x16x32_f16(akh1, ql[c][1], xx, 0,0,0);
        const float c2 = 1.0f/2048.0f;
        float s0 = fmaf(xx[0], c2, hh[0]);
        float s1 = fmaf(xx[1], c2, hh[1]);
        float s2 = fmaf(xx[2], c2, hh[2]);
        float s3 = fmaf(xx[3], c2, hh[3]);
        float tmax = fmaxf(fmaxf(s0,s1), fmaxf(s2,s3));
        if (tmax > mrun[c]) { mrun[c] = tmax; trun[c] = gtile; }
      }
    }
  }
#pragma unroll
  for (int c = 0; c < 2; ++c) {
#pragma unroll
    for (int mask = 16; mask <= 32; mask <<= 1) {
      float om = __shfl_xor(mrun[c], mask, 64);
      int   ot = __shfl_xor(trun[c], mask, 64);
      if (om > mrun[c] || (om == mrun[c] && ot < trun[c])) { mrun[c]=om; trun[c]=ot; }
    }
  }
  if (lane < 16) {
    size_t r = (size_t)js*ROWS + b*NN + i0 + lane;
    pm[r] = mrun[0]; pt[r] = trun[0];
  } else if (lane < 32) {
    size_t r = (size_t)js*ROWS + b*NN + i0 + 16 + (lane & 15);
    pm[r] = mrun[1]; pt[r] = trun[1];
  }
}

// ---------------- Kernel 2b: reduce splits + exact fp32 rescue --------------
__global__ __launch_bounds__(64) void rescue_kernel(
    const float* __restrict__ q, const float* __restrict__ k,
    const float* __restrict__ pm, const int* __restrict__ pt,
    int* __restrict__ idx) {
  const int r = blockIdx.x*64 + threadIdx.x;
  float m = -FLT_MAX; int t = 0;
#pragma unroll
  for (int js = 0; js < JSPLIT; ++js) {
    float om = pm[(size_t)js*ROWS + r];
    int   ot = pt[(size_t)js*ROWS + r];
    if (om > m) { m = om; t = ot; }
  }
  const int b = r >> 11;
  float4 qr[16];
  const float4* qp = (const float4*)(q + (size_t)r*64);
#pragma unroll
  for (int d4 = 0; d4 < 16; ++d4) qr[d4] = qp[d4];
  float best = -FLT_MAX; int bj = 0;
#pragma unroll 2
  for (int jj = 0; jj < 16; ++jj) {
    const int j = t*16 + jj;
    const float4* kp = (const float4*)(k + ((size_t)b*NN + j)*64);
    float a0=0.f,a1=0.f,a2=0.f,a3=0.f;
#pragma unroll
    for (int d4 = 0; d4 < 16; ++d4) {
      float4 kv = kp[d4], qv = qr[d4];
      a0 = fmaf(qv.x,kv.x,a0); a1 = fmaf(qv.y,kv.y,a1);
      a2 = fmaf(qv.z,kv.z,a2); a3 = fmaf(qv.w,kv.w,a3);
    }
    float dot = (a0+a1)+(a2+a3);
    if (dot > best) { best = dot; bj = j; }
  }
  idx[r] = bj;
}

// ---------------- Kernel 3: MFMA epilogue (no spills) -----------------------
// Block = 16 rows. MFMA1: mid = relu(norm@Wa + x@Wb + bin); MFMA2: rn = mid@W2.
// Fragment layouts identical to qkv/argmax (verified): A li->out-col, lg->K-octet;
// B li->row, d=kh*32+lg*8+e; D col=li=row, row=lg*4+reg=out-col-within-tile.
__global__ __launch_bounds__(256) void epilogue_kernel(
    const float* __restrict__ x, const float* __restrict__ v,
    const int* __restrict__ idx,
    const float* __restrict__ g1, const float* __restrict__ b1,
    const float* __restrict__ W1, const float* __restrict__ bin,
    const float* __restrict__ W2, const float* __restrict__ bout,
    const float* __restrict__ g2, const float* __restrict__ b2,
    float* __restrict__ out) {
  __shared__ float mids[16*68];    // mid tile [r][m]; later reused as out-stage
  __shared__ float2 sums[16*4];    // LN2 cross-wave partials
  const int tid = threadIdx.x, lane = tid & 63, wv = tid >> 6;
  const int li = lane & 15, lg = lane >> 4;
  const size_t r0 = (size_t)blockIdx.x * 16;
  const int rr = (int)r0 + li;               // this lane's row
  const int b  = rr >> 11;

  // A-fragments: Wa,Wb (out-col m = wv*16+li), W2 (out-col n = wv*16+li); K-octet by lg
  half8 wah[2], wal[2], wbh[2], wbl[2], w2h[2], w2l[2];
  const int ocol = wv*16 + li;
#pragma unroll
  for (int kh = 0; kh < 2; ++kh) {
#pragma unroll
    for (int e = 0; e < 8; ++e) {
      const int d = kh*32 + lg*8 + e;
      float wa = W1[d*64 + ocol] + W1[(128+d)*64 + ocol];
      float wb = W1[(64+d)*64 + ocol];
      float w2 = W2[d*64 + ocol];
      _Float16 h;
      h = (_Float16)wa; wah[kh][e]=h; wal[kh][e]=(_Float16)((wa-(float)h)*2048.f);
      h = (_Float16)wb; wbh[kh][e]=h; wbl[kh][e]=(_Float16)((wb-(float)h)*2048.f);
      h = (_Float16)w2; w2h[kh][e]=h; w2l[kh][e]=(_Float16)((w2-(float)h)*2048.f);
    }
  }
  // gather v[idx], load x row slice (B-frag layout: d = kh*32 + lg*8 + e)
  const int j = idx[rr];
  const float* vsrc = v + ((size_t)b*NN + j)*64 + lg*8;
  const float* xsrc = x + (size_t)rr*64 + lg*8;
  float vv[16], xv[16];
  *(float4*)&vv[0]  = *(const float4*)(vsrc);
  *(float4*)&vv[4]  = *(const float4*)(vsrc+4);
  *(float4*)&vv[8]  = *(const float4*)(vsrc+32);
  *(float4*)&vv[12] = *(const float4*)(vsrc+36);
  *(float4*)&xv[0]  = *(const float4*)(xsrc);
  *(float4*)&xv[4]  = *(const float4*)(xsrc+4);
  *(float4*)&xv[8]  = *(const float4*)(xsrc+32);
  *(float4*)&xv[12] = *(const float4*)(xsrc+36);
  // LN1: row sums via shfl over lg (lanes li, li+16, li+32, li+48 share row)
  float s = 0.f, s2 = 0.f;
#pragma unroll
  for (int e = 0; e < 16; ++e) { s += vv[e]; s2 += vv[e]*vv[e]; }
#pragma unroll
  for (int mask = 16; mask <= 32; mask <<= 1) {
    s  += __shfl_xor(s,  mask, 64);
    s2 += __shfl_xor(s2, mask, 64);
  }
  float mu  = s*(1.f/64.f);
  float inv = rsqrtf(s2*(1.f/64.f) - mu*mu + 1e-5f);
  float ga[16], bb[16];
  *(float4*)&ga[0]  = *(const float4*)(g1 + lg*8);
  *(float4*)&ga[4]  = *(const float4*)(g1 + lg*8 + 4);
  *(float4*)&ga[8]  = *(const float4*)(g1 + 32 + lg*8);
  *(float4*)&ga[12] = *(const float4*)(g1 + 32 + lg*8 + 4);
  *(float4*)&bb[0]  = *(const float4*)(b1 + lg*8);
  *(float4*)&bb[4]  = *(const float4*)(b1 + lg*8 + 4);
  *(float4*)&bb[8]  = *(const float4*)(b1 + 32 + lg*8);
  *(float4*)&bb[12] = *(const float4*)(b1 + 32 + lg*8 + 4);
  // split-3 convert norm and x fragments
  half8 nh[2], nl[2], xh[2], xl[2];
#pragma unroll
  for (int kh = 0; kh < 2; ++kh)
#pragma unroll
    for (int e = 0; e < 8; ++e) {
      float nvv = (vv[kh*8+e] - mu)*inv*ga[kh*8+e] + bb[kh*8+e];
      _Float16 h = (_Float16)nvv;
      nh[kh][e] = h; nl[kh][e] = (_Float16)((nvv - (float)h)*2048.f);
      float xvv = xv[kh*8+e];
      h = (_Float16)xvv;
      xh[kh][e] = h; xl[kh][e] = (_Float16)((xvv - (float)h)*2048.f);
    }
  const f32x4 Z = {0.f,0.f,0.f,0.f};
  const float c2 = 1.0f/2048.0f;
  // MFMA1: mid = norm@Wa + x@Wb
  f32x4 hh = __builtin_amdgcn_mfma_f32_16x16x32_f16(wah[0], nh[0], Z, 0,0,0);
  hh = __builtin_amdgcn_mfma_f32_16x16x32_f16(wah[1], nh[1], hh, 0,0,0);
  hh = __builtin_amdgcn_mfma_f32_16x16x32_f16(wbh[0], xh[0], hh, 0,0,0);
  hh = __builtin_amdgcn_mfma_f32_16x16x32_f16(wbh[1], xh[1], hh, 0,0,0);
  f32x4 xx = __builtin_amdgcn_mfma_f32_16x16x32_f16(wal[0], nh[0], Z, 0,0,0);
  xx = __builtin_amdgcn_mfma_f32_16x16x32_f16(wal[1], nh[1], xx, 0,0,0);
  xx = __builtin_amdgcn_mfma_f32_16x16x32_f16(wah[0], nl[0], xx, 0,0,0);
  xx = __builtin_amdgcn_mfma_f32_16x16x32_f16(wah[1], nl[1], xx, 0,0,0);
  xx = __builtin_amdgcn_mfma_f32_16x16x32_f16(wbl[0], xh[0], xx, 0,0,0);
  xx = __builtin_amdgcn_mfma_f32_16x16x32_f16(wbl[1], xh[1], xx, 0,0,0);
  xx = __builtin_amdgcn_mfma_f32_16x16x32_f16(wbh[0], xl[0], xx, 0,0,0);
  xx = __builtin_amdgcn_mfma_f32_16x16x32_f16(wbh[1], xl[1], xx, 0,0,0);
  float4 binv = *(const float4*)(bin + wv*16 + lg*4);
  float mv0 = fmaxf(fmaf(xx[0], c2, hh[0]) + binv.x, 0.f);
  float mv1 = fmaxf(fmaf(xx[1], c2, hh[1]) + binv.y, 0.f);
  float mv2 = fmaxf(fmaf(xx[2], c2, hh[2]) + binv.z, 0.f);
  float mv3 = fmaxf(fmaf(xx[3], c2, hh[3]) + binv.w, 0.f);
  // D: row = r0+li (col=li), m = wv*16 + lg*4 + reg  -> bounce through LDS
  *(float4*)&mids[li*68 + wv*16 + lg*4] = make_float4(mv0,mv1,mv2,mv3);
  __syncthreads();
  // B-frag of mid: row li, m = kh*32 + lg*8 + e
  half8 mh[2], ml[2];
#pragma unroll
  for (int kh = 0; kh < 2; ++kh) {
    float mm[8];
    *(float4*)&mm[0] = *(const float4*)&mids[li*68 + kh*32 + lg*8];
    *(float4*)&mm[4] = *(const float4*)&mids[li*68 + kh*32 + lg*8 + 4];
#pragma unroll
    for (int e = 0; e < 8; ++e) {
      _Float16 h = (_Float16)mm[e];
      mh[kh][e] = h; ml[kh][e] = (_Float16)((mm[e] - (float)h)*2048.f);
    }
  }
  __syncthreads();   // mids free for out-stage reuse
  // MFMA2: rn = mid@W2
  f32x4 h2 = __builtin_amdgcn_mfma_f32_16x16x32_f16(w2h[0], mh[0], Z, 0,0,0);
  h2 = __builtin_amdgcn_mfma_f32_16x16x32_f16(w2h[1], mh[1], h2, 0,0,0);
  f32x4 x2 = __builtin_amdgcn_mfma_f32_16x16x32_f16(w2l[0], mh[0], Z, 0,0,0);
  x2 = __builtin_amdgcn_mfma_f32_16x16x32_f16(w2l[1], mh[1], x2, 0,0,0);
  x2 = __builtin_amdgcn_mfma_f32_16x16x32_f16(w2h[0], ml[0], x2, 0,0,0);
  x2 = __builtin_amdgcn_mfma_f32_16x16x32_f16(w2h[1], ml[1], x2, 0,0,0);
  float4 boutv = *(const float4*)(bout + wv*16 + lg*4);
  float rn[4];
  rn[0] = fmaf(x2[0], c2, h2[0]) + boutv.x;
  rn[1] = fmaf(x2[1], c2, h2[1]) + boutv.y;
  rn[2] = fmaf(x2[2], c2, h2[2]) + boutv.z;
  rn[3] = fmaf(x2[3], c2, h2[3]) + boutv.w;
  // LN2: row r0+li, n spread over lg (shfl) AND wv (LDS)
  float ps = rn[0]+rn[1]+rn[2]+rn[3];
  float ps2 = rn[0]*rn[0]+rn[1]*rn[1]+rn[2]*rn[2]+rn[3]*rn[3];
#pragma unroll
  for (int mask = 16; mask <= 32; mask <<= 1) {
    ps  += __shfl_xor(ps,  mask, 64);
    ps2 += __shfl_xor(ps2, mask, 64);
  }
  if (lg == 0) sums[li*4 + wv] = make_float2(ps, ps2);
  __syncthreads();
  float ts = 0.f, ts2 = 0.f;
#pragma unroll
  for (int w = 0; w < 4; ++w) { float2 p = sums[li*4 + w]; ts += p.x; ts2 += p.y; }
  float mu2  = ts*(1.f/64.f);
  float inv2 = rsqrtf(ts2*(1.f/64.f) - mu2*mu2 + 1e-5f);
  float4 g2v = *(const float4*)(g2 + wv*16 + lg*4);
  float4 b2v = *(const float4*)(b2 + wv*16 + lg*4);
  float4 xnv = *(const float4*)(x + (size_t)rr*64 + wv*16 + lg*4);
  float4 ov;
  ov.x = (rn[0]-mu2)*inv2*g2v.x + b2v.x + xnv.x;
  ov.y = (rn[1]-mu2)*inv2*g2v.y + b2v.y + xnv.y;
  ov.z = (rn[2]-mu2)*inv2*g2v.z + b2v.z + xnv.z;
  ov.w = (rn[3]-mu2)*inv2*g2v.w + b2v.w + xnv.w;
  *(float4*)&mids[li*68 + wv*16 + lg*4] = ov;
  __syncthreads();
  // coalesced store: 16 rows x 64 cols = 256 float4
  const int row = tid >> 4, col = (tid & 15)*4;
  *(float4*)(out + r0*64 + tid*4) = *(const float4*)&mids[row*68 + col];
}

extern "C" void kernel_launch(void* const* d_in, const int* in_sizes, int n_in,
                              void* d_out, int out_size, void* d_ws, size_t ws_size,
                              hipStream_t stream) {
  const float* x    = (const float*)d_in[0];
  const float* Wq   = (const float*)d_in[1];
  const float* Wkv  = (const float*)d_in[2];
  const float* g1   = (const float*)d_in[3];
  const float* b1   = (const float*)d_in[4];
  const float* W1   = (const float*)d_in[5];
  const float* bin  = (const float*)d_in[6];
  const float* W2   = (const float*)d_in[7];
  const float* bout = (const float*)d_in[8];
  const float* g2   = (const float*)d_in[9];
  const float* b2   = (const float*)d_in[10];
  float* ws   = (float*)d_ws;
  float* q    = ws;
  float* k    = ws + 1048576;
  float* v    = ws + 2097152;
  float* pm   = ws + 3145728;              // [8][16384] f32
  int*   pt   = (int*)(ws + 3276800);      // [8][16384] i32
  int*   idx  = (int*)(ws + 3407872);      // [16384] i32

  qkv_kernel<<<ROWS/32, 256, 0, stream>>>(x, Wq, Wkv, q, k, v);
  argmax_mfma_kernel<<<dim3(16, JSPLIT, NB), 256, 0, stream>>>(q, k, pm, pt);
  rescue_kernel<<<ROWS/64, 64, 0, stream>>>(q, k, pm, pt, idx);
  epilogue_kernel<<<ROWS/16, 256, 0, stream>>>(x, v, idx, g1, b1, W1, bin,
                                               W2, bout, g2, b2, (float*)d_out);
}